// Round 5
// baseline (3191.507 us; speedup 1.0000x reference)
//
#include <hip/hip_runtime.h>

typedef _Float16 f16x8 __attribute__((ext_vector_type(8)));
typedef float f32x4 __attribute__((ext_vector_type(4)));

#define Dd  256
#define Hh  1024
#define ZSTR2 264     // 2-row z: stride f16 (132 dw = 4 mod 32 -> <=2-way, free)
#define ASTR2 1056    // 2-row act: stride f16 (528 dw = 16 mod 32 -> conflict-free)

// ---------- prep: pack weights fragment-major (per wave,tile,lane) ----------
// W1P[((w*8+nt)*8+kk)*512 + lane*8 + j] = W1[kk*32+q*8+j][w*128+nt*16+ln]
// (lane = q*16+ln). Consumer load = base + tile*1KB + lane*16B: fully coalesced.
__global__ void pack_w1_kernel(const float* __restrict__ W1, _Float16* __restrict__ W1P) {
    int gid = blockIdx.x * 256 + threadIdx.x;       // 262144 = 256*1024
    int h = gid & 1023, d = gid >> 10;              // coalesced read along h
    int w = h >> 7, nt = (h >> 4) & 7, ln = h & 15;
    int kk = d >> 5, q = (d >> 3) & 3, j = d & 7;
    W1P[(((w * 8 + nt) * 8 + kk) * 64 + q * 16 + ln) * 8 + j] = (_Float16)W1[d * 1024 + h];
}
// W2P[((w*2+t)*32+kk)*512 + lane*8 + j] = W2[kk*32+q*8+j][w*32+t*16+ln]
__global__ void pack_w2_kernel(const float* __restrict__ W2, _Float16* __restrict__ W2P) {
    int gid = blockIdx.x * 256 + threadIdx.x;       // 262144 = 1024*256
    int dcol = gid & 255, h = gid >> 8;             // coalesced read along dcol
    int w = dcol >> 5, t = (dcol >> 4) & 1, ln = dcol & 15;
    int kk = h >> 5, q = (h >> 3) & 3, j = h & 7;
    W2P[(((w * 2 + t) * 32 + kk) * 64 + q * 16 + ln) * 8 + j] = (_Float16)W2[h * 256 + dcol];
}

// ---------------- main: zero-sync, fragment-major streams, 16 waves/CU ----------------
// 512 blocks x 512 threads = 2 blocks/CU. Block owns 2 batch rows (replicated
// 8x across MFMA C-rows: row m holds batch m&1). Wave w owns H-slice w*128 and
// D-slice w*32. Weights stream as sequential 1KB fragment tiles; per-wave
// stream unchanged at 128KB/eval but waves/CU doubles and every load is a
// full-line coalesced read. Numerics identical to round 4 (same values, same
// MFMA order).
__global__ __launch_bounds__(512, 4) void ode_kernel(
    const float* __restrict__ z0, const float* __restrict__ tv,
    const float* __restrict__ b1, const float* __restrict__ b2,
    const _Float16* __restrict__ W1P,   // fragment-major, 512 KB
    const _Float16* __restrict__ W2P,   // fragment-major, 512 KB
    float* __restrict__ out) {
    __shared__ _Float16 z2[2][ZSTR2];    // [batch&1][256]
    __shared__ _Float16 act2[2][ASTR2];  // [batch&1][1024]

    const int tid  = threadIdx.x;
    const int w    = tid >> 6;
    const int lane = tid & 63;
    const int ln   = lane & 15;
    const int q    = lane >> 4;
    const int m0   = blockIdx.x * 2;

    const float h = (tv[1] - tv[0]) * 0.125f;

    float bb1[8];
#pragma unroll
    for (int nt = 0; nt < 8; ++nt) bb1[nt] = b1[w * 128 + nt * 16 + ln];
    float bb2v[2];
#pragma unroll
    for (int t = 0; t < 2; ++t) bb2v[t] = b2[w * 32 + t * 16 + ln];

    // per-wave fragment streams: 64 tiles of 512 f16 each (1KB), sequential
    const _Float16* W1w = W1P + (size_t)(w * 64) * 512 + lane * 8;
    const _Float16* W2w = W2P + (size_t)(w * 64) * 512 + lane * 8;

    // RK4 state (replicated): z[t][r] = z[batch m0+(r&1)][w*32+t*16+ln]
    f32x4 z[2], zsum[2];
#pragma unroll
    for (int t = 0; t < 2; ++t)
#pragma unroll
        for (int r = 0; r < 4; ++r)
            z[t][r] = z0[(m0 + (r & 1)) * Dd + w * 32 + t * 16 + ln];
    if (q == 0) {
#pragma unroll
        for (int t = 0; t < 2; ++t)
#pragma unroll
            for (int r = 0; r < 2; ++r)
                z2[r][w * 32 + t * 16 + ln] = (_Float16)z[t][r];
    }
    __syncthreads();

#pragma unroll 1
    for (int ev = 0; ev < 32; ++ev) {
        const int e = ev & 3;

        // ---- GEMM1: act[:, w*128..+128) = tanh(z @ W1 + b1) ----
        f16x8 a1[8];
#pragma unroll
        for (int kk = 0; kk < 8; ++kk)
            a1[kk] = *(const f16x8*)&z2[ln & 1][kk * 32 + q * 8];

#pragma unroll
        for (int nt = 0; nt < 8; ++nt) {
            f32x4 acc = {0.f, 0.f, 0.f, 0.f};
#pragma unroll
            for (int kk = 0; kk < 8; ++kk)
                acc = __builtin_amdgcn_mfma_f32_16x16x32_f16(
                        a1[kk], *(const f16x8*)&W1w[(nt * 8 + kk) * 512],
                        acc, 0, 0, 0);
            // all quads hold identical values for C-row parity r&1; quad 0 stores
#pragma unroll
            for (int r = 0; r < 2; ++r) {
                float x = acc[r] + bb1[nt];
                float ex = __expf(2.0f * x);
                float th = 1.0f - 2.0f / (ex + 1.0f);
                if (q == 0)
                    act2[r][w * 128 + nt * 16 + ln] = (_Float16)th;
            }
        }
        __syncthreads();

        // ---- GEMM2: k[:, w*32..+32) = act @ W2 + b2 ----
        f32x4 acc2[2] = {{0.f, 0.f, 0.f, 0.f}, {0.f, 0.f, 0.f, 0.f}};
#pragma unroll
        for (int kk = 0; kk < 32; ++kk) {
            f16x8 a2 = *(const f16x8*)&act2[ln & 1][kk * 32 + q * 8];
#pragma unroll
            for (int t = 0; t < 2; ++t)
                acc2[t] = __builtin_amdgcn_mfma_f32_16x16x32_f16(
                            a2, *(const f16x8*)&W2w[(t * 32 + kk) * 512],
                            acc2[t], 0, 0, 0);
        }

        // ---- RK4 epilogue (registers, replicated) ----
#pragma unroll
        for (int t = 0; t < 2; ++t) {
            f32x4 kv, za;
#pragma unroll
            for (int r = 0; r < 4; ++r) kv[r] = acc2[t][r] + bb2v[t];
            if (e == 0) {
                zsum[t] = kv;
            } else if (e == 3) {
#pragma unroll
                for (int r = 0; r < 4; ++r) zsum[t][r] += kv[r];
            } else {
#pragma unroll
                for (int r = 0; r < 4; ++r) zsum[t][r] += 2.0f * kv[r];
            }
            if (e < 3) {
                const float c = (e == 2) ? h : 0.5f * h;
#pragma unroll
                for (int r = 0; r < 4; ++r) za[r] = z[t][r] + c * kv[r];
            } else {
#pragma unroll
                for (int r = 0; r < 4; ++r) {
                    z[t][r] += (h * (1.0f / 6.0f)) * zsum[t][r];
                    za[r] = z[t][r];
                }
            }
            if (q == 0) {
#pragma unroll
                for (int r = 0; r < 2; ++r)
                    z2[r][w * 32 + t * 16 + ln] = (_Float16)za[r];
            }
        }
        __syncthreads();
    }

    // final state -> out (quad 0, rows 0..1)
    if (q == 0) {
#pragma unroll
        for (int t = 0; t < 2; ++t)
#pragma unroll
            for (int r = 0; r < 2; ++r)
                out[(m0 + r) * Dd + w * 32 + t * 16 + ln] = z[t][r];
    }
}

extern "C" void kernel_launch(void* const* d_in, const int* in_sizes, int n_in,
                              void* d_out, int out_size, void* d_ws, size_t ws_size,
                              hipStream_t stream) {
    const float* z0 = (const float*)d_in[0];
    const float* tv = (const float*)d_in[1];
    const float* W1 = (const float*)d_in[2];   // [256][1024]
    const float* b1 = (const float*)d_in[3];   // [1024]
    const float* W2 = (const float*)d_in[4];   // [1024][256]
    const float* b2 = (const float*)d_in[5];   // [256]
    float* out = (float*)d_out;

    _Float16* W1P = (_Float16*)d_ws;           // 512 KB fragment-major
    _Float16* W2P = W1P + Hh * Dd;             // 512 KB fragment-major

    pack_w1_kernel<<<1024, 256, 0, stream>>>(W1, W1P);
    pack_w2_kernel<<<1024, 256, 0, stream>>>(W2, W2P);

    ode_kernel<<<512, 512, 0, stream>>>(z0, tv, b1, b2, W1P, W2P, out);
}

// Round 7
// 552.856 us; speedup vs baseline: 5.7728x; 5.7728x over previous
//
#include <hip/hip_runtime.h>

typedef _Float16 f16x8 __attribute__((ext_vector_type(8)));
typedef float f32x4 __attribute__((ext_vector_type(4)));

#define Dd 256
#define Hh 1024

// ---------- prep: pack weights fragment-major ----------
// W1P tile (w,nt,kk) = ((w*8+nt)*8+kk): lane(q*16+ln)*8+j holds
//   W1[kk*32+q*8+j][w*128+nt*16+ln]  (B-fragment for 16x16x32 MFMA)
__global__ void pack_w1_kernel(const float* __restrict__ W1, _Float16* __restrict__ W1P) {
    int gid = blockIdx.x * 256 + threadIdx.x;       // 256*1024 elements
    int h = gid & 1023, d = gid >> 10;
    int w = h >> 7, nt = (h >> 4) & 7, ln = h & 15;
    int kk = d >> 5, q = (d >> 3) & 3, j = d & 7;
    W1P[(((w * 8 + nt) * 8 + kk) * 64 + q * 16 + ln) * 8 + j] = (_Float16)W1[d * 1024 + h];
}
// W2P tile (w,kk,t) = ((w*32+kk)*2+t): consumption-linear for GEMM2
__global__ void pack_w2_kernel(const float* __restrict__ W2, _Float16* __restrict__ W2P) {
    int gid = blockIdx.x * 256 + threadIdx.x;       // 1024*256 elements
    int dcol = gid & 255, h = gid >> 8;
    int w = dcol >> 5, t = (dcol >> 4) & 1, ln = dcol & 15;
    int kk = h >> 5, q = (h >> 3) & 3, j = h & 7;
    W2P[(((w * 32 + kk) * 2 + t) * 64 + q * 16 + ln) * 8 + j] = (_Float16)W2[h * 256 + dcol];
}

typedef __attribute__((address_space(1))) const unsigned int gu32;
typedef __attribute__((address_space(3))) unsigned int lu32;

// async 1KB fragment tile: global (per-lane base+lane*16) -> LDS (uniform base,
// HW scatters lane*16). Zero VGPR cost; tracked by vmcnt.
__device__ __forceinline__ void async_tile(const _Float16* g, _Float16* l, int lane) {
    __builtin_amdgcn_global_load_lds((gu32*)(g + lane * 8), (lu32*)l, 16, 0, 0);
}

// ---------------- main: 64 blocks x 512 thr, async-LDS weight ring ----------------
// Block owns 16 batch rows, whole solve, zero inter-block sync. Wave w owns
// H-slice [w*128,+128) (GEMM1) and D-slice [w*32,+32) (GEMM2). Per eval each
// wave streams 32 chunks (4 KB = 4 fragment tiles each): 16 W1 + 16 W2, via a
// 3-slot LDS ring. RAW: s_waitcnt vmcnt(8/4/0) — robust even against stray
// scratch VMEM ops (retire-in-order argument). WAR (round-6 bug): the slot
// overwritten by ISSUE(c+3) is the one chunk c was just read from; the
// lgkmcnt(0) guard at the top of ISSUE retires all prior ds_reads before the
// DMA can issue, and its memory clobber stops the compiler hoisting the DMA
// above the reads.
__global__ __launch_bounds__(512, 2) void ode_kernel(
    const float* __restrict__ z0, const float* __restrict__ tv,
    const float* __restrict__ b1, const float* __restrict__ b2,
    const _Float16* __restrict__ W1P, const _Float16* __restrict__ W2P,
    float* __restrict__ out) {
    __shared__ _Float16 wbuf[8][3][2048];    // 96 KB: per-wave 3-slot ring
    __shared__ _Float16 act_lds[16][1032];   // 33 KB (+8 pad: 2-way banks, free)
    __shared__ _Float16 z_lds[16][264];      // 8.25 KB

    const int tid  = threadIdx.x;
    const int w    = tid >> 6;
    const int lane = tid & 63;
    const int ln   = lane & 15;
    const int q    = lane >> 4;
    const int m0   = blockIdx.x * 16;

    const float h = (tv[1] - tv[0]) * 0.125f;

    float bb1[8];
#pragma unroll
    for (int nt = 0; nt < 8; ++nt) bb1[nt] = b1[w * 128 + nt * 16 + ln];
    float bb2v[2];
#pragma unroll
    for (int t = 0; t < 2; ++t) bb2v[t] = b2[w * 32 + t * 16 + ln];

    const _Float16* W1w = W1P + (size_t)(w * 64) * 512;   // 64 KB: tiles (nt,kk)
    const _Float16* W2w = W2P + (size_t)(w * 64) * 512;   // 64 KB: tiles (kk,t)

// chunk c (0..31): source 4 KB; dest slot c%3 of this wave's ring.
// lgkmcnt(0) guard: all prior ds_reads retired before DMA overwrite (WAR fix).
#define ISSUE(cc) { asm volatile("s_waitcnt lgkmcnt(0)" ::: "memory");               \
    const _Float16* gsrc = ((cc) < 16) ? (W1w + (cc) * 2048)                         \
                                       : (W2w + ((cc) - 16) * 2048);                 \
    _Float16* ldst = &wbuf[w][(cc) % 3][0];                                          \
    _Pragma("unroll")                                                                \
    for (int ii = 0; ii < 4; ++ii) async_tile(gsrc + ii * 512, ldst + ii * 512, lane); }
// before consuming chunk cc: oldest outstanding chunk must have landed
#define WAITC(cc) { if ((cc) <= 29)      asm volatile("s_waitcnt vmcnt(8)" ::: "memory"); \
                    else if ((cc) == 30) asm volatile("s_waitcnt vmcnt(4)" ::: "memory"); \
                    else                 asm volatile("s_waitcnt vmcnt(0)" ::: "memory"); }

    // RK4 state in registers (C-layout): z[t][r] = z[m0+q*4+r][w*32+t*16+ln]
    f32x4 z[2], zsum[2];
#pragma unroll
    for (int t = 0; t < 2; ++t)
#pragma unroll
        for (int r = 0; r < 4; ++r)
            z[t][r] = z0[(m0 + q * 4 + r) * Dd + w * 32 + t * 16 + ln];
#pragma unroll
    for (int t = 0; t < 2; ++t)
#pragma unroll
        for (int r = 0; r < 4; ++r)
            z_lds[q * 4 + r][w * 32 + t * 16 + ln] = (_Float16)z[t][r];
    __syncthreads();

#pragma unroll 1
    for (int ev = 0; ev < 32; ++ev) {
        const int e = ev & 3;

        // prime the ring (end-of-eval barrier drained previous eval's traffic)
        ISSUE(0); ISSUE(1); ISSUE(2);

        // ---- GEMM1: act[:, w*128..+128) = tanh(z @ W1 + b1) ----
        f16x8 a1[8];
#pragma unroll
        for (int kk = 0; kk < 8; ++kk)
            a1[kk] = *(const f16x8*)&z_lds[ln][kk * 32 + q * 8];

#pragma unroll
        for (int nt = 0; nt < 8; ++nt) {
            f32x4 acc = {0.f, 0.f, 0.f, 0.f};
#pragma unroll
            for (int half = 0; half < 2; ++half) {
                const int c = nt * 2 + half;      // chunk: tiles kk = half*4..+3
                WAITC(c);
                const _Float16* tb = &wbuf[w][c % 3][0];
#pragma unroll
                for (int i = 0; i < 4; ++i) {
                    f16x8 bf = *(const f16x8*)&tb[i * 512 + lane * 8];
                    acc = __builtin_amdgcn_mfma_f32_16x16x32_f16(a1[half * 4 + i], bf, acc, 0, 0, 0);
                }
                if (c + 3 <= 31) ISSUE(c + 3);
            }
#pragma unroll
            for (int r = 0; r < 4; ++r) {
                float x = acc[r] + bb1[nt];
                float ex = __expf(2.0f * x);
                act_lds[q * 4 + r][w * 128 + nt * 16 + ln] =
                    (_Float16)(1.0f - 2.0f / (ex + 1.0f));
            }
        }
        __syncthreads();   // act ready; also drains in-flight W2 chunks 16..18 (stay valid)

        // ---- GEMM2: k[:, w*32..+32) = act @ W2 + b2 ----
        f32x4 acc2[2] = {{0.f, 0.f, 0.f, 0.f}, {0.f, 0.f, 0.f, 0.f}};
#pragma unroll
        for (int cp = 0; cp < 16; ++cp) {
            const int c = 16 + cp;               // chunk: kk pair {2cp,2cp+1} x t{0,1}
            WAITC(c);
            const _Float16* tb = &wbuf[w][c % 3][0];
#pragma unroll
            for (int half = 0; half < 2; ++half) {
                const int kk = cp * 2 + half;
                f16x8 a2 = *(const f16x8*)&act_lds[ln][kk * 32 + q * 8];
#pragma unroll
                for (int t = 0; t < 2; ++t) {
                    f16x8 bf = *(const f16x8*)&tb[(half * 2 + t) * 512 + lane * 8];
                    acc2[t] = __builtin_amdgcn_mfma_f32_16x16x32_f16(a2, bf, acc2[t], 0, 0, 0);
                }
            }
            if (c + 3 <= 31) ISSUE(c + 3);
        }

        // ---- RK4 epilogue (registers) ----
#pragma unroll
        for (int t = 0; t < 2; ++t) {
            f32x4 kv, za;
#pragma unroll
            for (int r = 0; r < 4; ++r) kv[r] = acc2[t][r] + bb2v[t];
            if (e == 0) {
                zsum[t] = kv;
            } else if (e == 3) {
#pragma unroll
                for (int r = 0; r < 4; ++r) zsum[t][r] += kv[r];
            } else {
#pragma unroll
                for (int r = 0; r < 4; ++r) zsum[t][r] += 2.0f * kv[r];
            }
            if (e < 3) {
                const float c = (e == 2) ? h : 0.5f * h;
#pragma unroll
                for (int r = 0; r < 4; ++r) za[r] = z[t][r] + c * kv[r];
            } else {
#pragma unroll
                for (int r = 0; r < 4; ++r) {
                    z[t][r] += (h * (1.0f / 6.0f)) * zsum[t][r];
                    za[r] = z[t][r];
                }
            }
#pragma unroll
            for (int r = 0; r < 4; ++r)
                z_lds[q * 4 + r][w * 32 + t * 16 + ln] = (_Float16)za[r];
        }
        __syncthreads();   // z ready for next eval (drains stragglers)
    }

#pragma unroll
    for (int t = 0; t < 2; ++t)
#pragma unroll
        for (int r = 0; r < 4; ++r)
            out[(m0 + q * 4 + r) * Dd + w * 32 + t * 16 + ln] = z[t][r];
#undef ISSUE
#undef WAITC
}

extern "C" void kernel_launch(void* const* d_in, const int* in_sizes, int n_in,
                              void* d_out, int out_size, void* d_ws, size_t ws_size,
                              hipStream_t stream) {
    const float* z0 = (const float*)d_in[0];
    const float* tv = (const float*)d_in[1];
    const float* W1 = (const float*)d_in[2];   // [256][1024]
    const float* b1 = (const float*)d_in[3];   // [1024]
    const float* W2 = (const float*)d_in[4];   // [1024][256]
    const float* b2 = (const float*)d_in[5];   // [256]
    float* out = (float*)d_out;

    _Float16* W1P = (_Float16*)d_ws;           // 512 KB fragment-major
    _Float16* W2P = W1P + Hh * Dd;             // 512 KB fragment-major

    pack_w1_kernel<<<1024, 256, 0, stream>>>(W1, W1P);
    pack_w2_kernel<<<1024, 256, 0, stream>>>(W2, W2P);

    ode_kernel<<<64, 512, 0, stream>>>(z0, tv, b1, b2, W1P, W2P, out);
}